// Round 5
// baseline (179.065 us; speedup 1.0000x reference)
//
#include <hip/hip_runtime.h>
#include <hip/hip_bf16.h>

#define BB 16
#define CC 512
#define LL 2048

typedef float f32x4 __attribute__((ext_vector_type(4)));
typedef short s16x8 __attribute__((ext_vector_type(8)));

static __device__ __forceinline__ float bf2f(unsigned short u) {
    union { unsigned int i; float f; } v; v.i = ((unsigned int)u) << 16; return v.f;
}
static __device__ __forceinline__ unsigned short f2bf(float f) {
    union { float fv; unsigned int i; } v; v.fv = f;
    unsigned int x = v.i;
    return (unsigned short)((x + 0x7FFFu + ((x >> 16) & 1u)) >> 16);  // RNE
}

// ---------------- K0: cast gate_w f32 -> bf16 [512][512] ----------------
__global__ void k0_cast(const float* __restrict__ gw, unsigned short* __restrict__ gwb) {
    int i = blockIdx.x * 256 + threadIdx.x;
    if (i < CC * CC) gwb[i] = f2bf(gw[i]);
}

// ------- K1: RMS over C per (b,l); write x_norm^T bf16 [B][L][C] + adx = sum_c x*lw -------
#define K1_ST 520   // ushort stride (1040 B, 16B-aligned)
__global__ __launch_bounds__(256) void k1_rms_t(
    const float* __restrict__ x, const float* __restrict__ pre_w,
    const float* __restrict__ lw,
    unsigned short* __restrict__ xnt, float* __restrict__ adx) {
    __shared__ unsigned short tile[32 * K1_ST];   // [l][c] bf16, 33.3 KB
    __shared__ float red[32 * 33];
    __shared__ float red2[32 * 33];
    __shared__ float pwS[CC];
    __shared__ float lwS[CC];
    __shared__ float ivS[32];
    const int tid = threadIdx.x;
    const int b  = blockIdx.x >> 6;      // 64 l-tiles of 32
    const int lt = blockIdx.x & 63;
    const int l0 = lt * 32;
    const float* xb = x + (size_t)(b * CC) * LL + l0;

    for (int i = tid; i < CC; i += 256) { pwS[i] = pre_w[i]; lwS[i] = lw[i]; }
    __syncthreads();

    const int lq = tid & 7;      // l-quad: l = lq*4..+3
    const int cr = tid >> 3;     // 0..31
    f32x4 ssq = {0.f, 0.f, 0.f, 0.f};
    f32x4 sdx = {0.f, 0.f, 0.f, 0.f};
    #pragma unroll
    for (int p = 0; p < 16; ++p) {
        int c = p * 32 + cr;
        float lwc = lwS[c];
        f32x4 v = *(const f32x4*)(xb + (size_t)c * LL + lq * 4);
        #pragma unroll
        for (int r = 0; r < 4; ++r) {
            ssq[r] += v[r] * v[r];
            sdx[r] += v[r] * lwc;
            tile[(lq * 4 + r) * K1_ST + c] = f2bf(v[r]);
        }
    }
    #pragma unroll
    for (int r = 0; r < 4; ++r) {
        red[(lq * 4 + r) * 33 + cr]  = ssq[r];
        red2[(lq * 4 + r) * 33 + cr] = sdx[r];
    }
    __syncthreads();
    if (tid < 32) {
        float s = 0.f, sa = 0.f;
        #pragma unroll
        for (int g = 0; g < 32; ++g) { s += red[tid * 33 + g]; sa += red2[tid * 33 + g]; }
        ivS[tid] = rsqrtf(s * (1.0f / CC) + 1e-5f);
        adx[b * LL + l0 + tid] = sa;
    }
    __syncthreads();
    unsigned short* xo = xnt + ((size_t)b * LL + l0) * CC;
    #pragma unroll
    for (int p = 0; p < 8; ++p) {
        int g = p * 256 + tid;          // 2048 granules of 8 ushorts
        int l = g >> 6, c8 = (g & 63) * 8;
        s16x8 t = *(const s16x8*)&tile[l * K1_ST + c8];
        f32x4 w0 = *(const f32x4*)&pwS[c8];
        f32x4 w1 = *(const f32x4*)&pwS[c8 + 4];
        float iv = ivS[l];
        s16x8 o;
        #pragma unroll
        for (int r = 0; r < 4; ++r) {
            o[r]     = (short)f2bf(bf2f((unsigned short)t[r])     * iv * w0[r]);
            o[r + 4] = (short)f2bf(bf2f((unsigned short)t[r + 4]) * iv * w1[r]);
        }
        *(s16x8*)(xo + (size_t)l * CC + c8) = o;
    }
}

// ------- K2_fused: GEMM(all 512 d) + SiLU-gate + conv*gate + post-RMS + logits -------
// BM=512, BN=128 l, BK=32, 16 K-tiles. 8 waves (4M x 2N: 128d x 64l each).
// 3-buffer LDS staging, 2-tiles-ahead prefetch, counted vmcnt(10) (T4).
// Epilogue: 4 c-chunks of 128; xn re-staged [l][c] with halo; gate via LDS bf16.
__global__ __launch_bounds__(512, 2) void k2_fused(
    const unsigned short* __restrict__ gwb,   // A [512][512] (d,c)
    const unsigned short* __restrict__ xnt,   // B^T [B][2048][512] (l,c)
    const float* __restrict__ gate_b,
    const float* __restrict__ cw0, const float* __restrict__ cb0,
    const float* __restrict__ cw1, const float* __restrict__ cb1,
    const float* __restrict__ cw2, const float* __restrict__ cb2,
    const float* __restrict__ post_w, const float* __restrict__ lw,
    const float* __restrict__ adx, float* __restrict__ out) {
    union Sm {
        struct { unsigned short A[3][512 * 32]; unsigned short B[3][128 * 32]; } g;  // 120 KB
        struct { unsigned short xnc[136 * 128]; unsigned short gS[128 * 128]; } e;   // 66 KB
    };
    __shared__ Sm sm;
    const int tid = threadIdx.x;
    const int w = tid >> 6, lane = tid & 63;
    const int lo = lane & 15, hi = lane >> 4;
    const int wm = w >> 1, wn = w & 1;          // 4M x 2N waves
    const int lt = blockIdx.x, b = blockIdx.z;
    const int l0 = lt * 128;
    const unsigned short* Ab = gwb;
    const unsigned short* Bb = xnt + (size_t)b * LL * CC;

    // ---- GEMM staging: linear LDS dest (gload_lds), pre-swizzled source ----
    // granule XOR: stored[gin] = src[gin ^ ((row>>1)&3)]; frag reads invert it.
    #define STG(kt_, buf_)                                                            \
        {                                                                             \
            _Pragma("unroll")                                                         \
            for (int r_ = 0; r_ < 4; ++r_) {                                          \
                int row_ = (tid >> 2) + r_ * 128, gin_ = tid & 3;                     \
                __builtin_amdgcn_global_load_lds(                                     \
                    (const __attribute__((address_space(1))) void*)(Ab + (size_t)row_ * CC + (kt_) * 32 + ((gin_ ^ ((row_ >> 1) & 3)) * 8)), \
                    (__attribute__((address_space(3))) void*)(&sm.g.A[buf_][(row_ * 32 + gin_ * 8)]), \
                    16, 0, 0);                                                        \
            }                                                                         \
            {                                                                         \
                int row_ = tid >> 2, gin_ = tid & 3;                                  \
                __builtin_amdgcn_global_load_lds(                                     \
                    (const __attribute__((address_space(1))) void*)(Bb + (size_t)(l0 + row_) * CC + (kt_) * 32 + ((gin_ ^ ((row_ >> 1) & 3)) * 8)), \
                    (__attribute__((address_space(3))) void*)(&sm.g.B[buf_][tid * 8]), \
                    16, 0, 0);                                                        \
            }                                                                         \
        }

    f32x4 acc[8][4] = {};
    const int fsw = (lo >> 1) & 3;     // frag-read granule swizzle

    STG(0, 0);
    STG(1, 1);
    #pragma unroll
    for (int kt = 0; kt < 16; ++kt) {
        const int buf = kt % 3;
        if (kt < 14) STG(kt + 2, (kt + 2) % 3);
        if (kt < 14)      asm volatile("s_waitcnt vmcnt(10)" ::: "memory");
        else if (kt == 14) asm volatile("s_waitcnt vmcnt(5)" ::: "memory");
        else               asm volatile("s_waitcnt vmcnt(0)" ::: "memory");
        __builtin_amdgcn_s_barrier();
        s16x8 af[8], bfr[4];
        #pragma unroll
        for (int mi = 0; mi < 8; ++mi)
            af[mi] = *(const s16x8*)&sm.g.A[buf][(wm * 128 + mi * 16 + lo) * 32 + ((hi ^ fsw) * 8)];
        #pragma unroll
        for (int ni = 0; ni < 4; ++ni)
            bfr[ni] = *(const s16x8*)&sm.g.B[buf][(wn * 64 + ni * 16 + lo) * 32 + ((hi ^ fsw) * 8)];
        __builtin_amdgcn_s_setprio(1);
        #pragma unroll
        for (int mi = 0; mi < 8; ++mi)
            #pragma unroll
            for (int ni = 0; ni < 4; ++ni)
                acc[mi][ni] = __builtin_amdgcn_mfma_f32_16x16x32_bf16(
                    af[mi], bfr[ni], acc[mi][ni], 0, 0, 0);
        __builtin_amdgcn_s_setprio(0);
        asm volatile("" ::: "memory");
        __builtin_amdgcn_s_barrier();
    }
    #undef STG

    // ---- bias + SiLU, pack gate to bf16 in regs (frees acc) ----
    unsigned int gpk[8][4][2];
    #pragma unroll
    for (int mi = 0; mi < 8; ++mi) {
        f32x4 gb4 = *(const f32x4*)(gate_b + wm * 128 + mi * 16 + hi * 4);
        #pragma unroll
        for (int ni = 0; ni < 4; ++ni) {
            f32x4 z = acc[mi][ni] + gb4;
            float s0 = z[0] / (1.0f + __expf(-z[0]));
            float s1 = z[1] / (1.0f + __expf(-z[1]));
            float s2 = z[2] / (1.0f + __expf(-z[2]));
            float s3 = z[3] / (1.0f + __expf(-z[3]));
            gpk[mi][ni][0] = (unsigned int)f2bf(s0) | ((unsigned int)f2bf(s1) << 16);
            gpk[mi][ni][1] = (unsigned int)f2bf(s2) | ((unsigned int)f2bf(s3) << 16);
        }
    }

    // ---- fused epilogue over 4 c-chunks of 128 ----
    float pass[4] = {}, padp[4] = {};
    const int cg = tid & 15, o = tid >> 4;    // c8-group, l-quad owner (0..31)
    #pragma unroll
    for (int q = 0; q < 4; ++q) {
        // stage xn chunk [136 l][128 c] bf16, pre-swizzled source (granule ^ (row&7))
        #pragma unroll
        for (int r = 0; r < 5; ++r) {
            int gi = tid + r * 512;
            if (gi < 2176) {
                int row = gi >> 4, gin = gi & 15;
                int lg = l0 - 4 + row;
                lg = lg < 0 ? 0 : (lg > LL - 1 ? LL - 1 : lg);
                __builtin_amdgcn_global_load_lds(
                    (const __attribute__((address_space(1))) void*)(Bb + (size_t)lg * CC + q * 128 + ((gin ^ (row & 7)) * 8)),
                    (__attribute__((address_space(3))) void*)(&sm.e.xnc[gi * 8]),
                    16, 0, 0);
            }
        }
        asm volatile("s_waitcnt vmcnt(0)" ::: "memory");
        __builtin_amdgcn_s_barrier();
        // zero-pad halo rows at sequence edges (whole rows, swizzle-agnostic)
        if (l0 == 0 && tid < 64) {
            s16x8 z8 = {};
            *(s16x8*)&sm.e.xnc[(tid >> 4) * 128 + (tid & 15) * 8] = z8;
        }
        if (l0 == LL - 128 && tid < 64) {
            s16x8 z8 = {};
            *(s16x8*)&sm.e.xnc[(132 + (tid >> 4)) * 128 + (tid & 15) * 8] = z8;
        }
        // gate chunk -> LDS (waves owning this d-range), XOR (l&7)<<3 on short offset
        if (wm == q) {
            #pragma unroll
            for (int mi = 0; mi < 8; ++mi)
                #pragma unroll
                for (int ni = 0; ni < 4; ++ni) {
                    int lg = wn * 64 + ni * 16 + lo;
                    int coff = (mi * 16 + hi * 4) ^ ((lg & 7) << 3);
                    *(uint2*)&sm.e.gS[lg * 128 + coff] = make_uint2(gpk[mi][ni][0], gpk[mi][ni][1]);
                }
        }
        __builtin_amdgcn_s_barrier();
        // compute: thread owns c8-group cg, l-quad o*4..+3
        s16x8 xr[12];
        #pragma unroll
        for (int t = 0; t < 12; ++t) {
            int row = o * 4 + t;
            xr[t] = *(const s16x8*)&sm.e.xnc[row * 128 + ((cg ^ (row & 7)) * 8)];
        }
        s16x8 gr[4];
        #pragma unroll
        for (int i = 0; i < 4; ++i) {
            int lg = o * 4 + i;
            gr[i] = *(const s16x8*)&sm.e.gS[lg * 128 + ((cg * 8) ^ ((lg & 7) << 3))];
        }
        #pragma unroll
        for (int j = 0; j < 8; ++j) {
            int c = q * 128 + cg * 8 + j;
            float t10 = cw0[c * 3], t11 = cw0[c * 3 + 1], t12 = cw0[c * 3 + 2];
            float t20 = cw1[c * 3], t21 = cw1[c * 3 + 1], t22 = cw1[c * 3 + 2];
            float t40 = cw2[c * 3], t41 = cw2[c * 3 + 1], t42 = cw2[c * 3 + 2];
            float bias = cb0[c] + cb1[c] + cb2[c];
            float tc = t11 + t21 + t41;
            float pwlw = post_w[c] * lw[c];
            float xf[12];
            #pragma unroll
            for (int t = 0; t < 12; ++t) xf[t] = bf2f((unsigned short)xr[t][j]);
            #pragma unroll
            for (int i = 0; i < 4; ++i) {
                float s = t40 * xf[i] + t20 * xf[i + 2] + t10 * xf[i + 3]
                        + tc * xf[i + 4] + t12 * xf[i + 5] + t22 * xf[i + 6]
                        + t42 * xf[i + 8];
                float p = (s + bias) * bf2f((unsigned short)gr[i][j]);
                pass[i] += p * p;
                padp[i] += p * pwlw;
            }
        }
        asm volatile("" ::: "memory");
        __builtin_amdgcn_s_barrier();
    }
    // reduce over the 16 c-groups (lane bits 0..3)
    #pragma unroll
    for (int m = 1; m < 16; m <<= 1) {
        #pragma unroll
        for (int i = 0; i < 4; ++i) {
            pass[i] += __shfl_xor(pass[i], m, 64);
            padp[i] += __shfl_xor(padp[i], m, 64);
        }
    }
    if (cg == 0) {
        #pragma unroll
        for (int i = 0; i < 4; ++i) {
            int lg = l0 + o * 4 + i;
            out[(size_t)b * LL + lg] = adx[b * LL + lg]
                + rsqrtf(pass[i] * (1.0f / CC) + 1e-5f) * padp[i];
        }
    }
}

extern "C" void kernel_launch(void* const* d_in, const int* in_sizes, int n_in,
                              void* d_out, int out_size, void* d_ws, size_t ws_size,
                              hipStream_t stream) {
    const float* x      = (const float*)d_in[1];
    const float* pre_w  = (const float*)d_in[2];
    const float* cw0    = (const float*)d_in[3];
    const float* cb0    = (const float*)d_in[4];
    const float* cw1    = (const float*)d_in[5];
    const float* cb1    = (const float*)d_in[6];
    const float* cw2    = (const float*)d_in[7];
    const float* cb2    = (const float*)d_in[8];
    const float* gw     = (const float*)d_in[9];
    const float* gb     = (const float*)d_in[10];
    const float* post_w = (const float*)d_in[11];
    const float* lw     = (const float*)d_in[12];
    float* out = (float*)d_out;

    // ws: gwb 0..0.5MB | xnt 0.5..34MB | adx +128KB
    char* ws = (char*)d_ws;
    unsigned short* gwb = (unsigned short*)(ws);
    unsigned short* xnt = (unsigned short*)(ws + 524288);
    float*          adx = (float*)(ws + 524288 + 33554432);

    hipLaunchKernelGGL(k0_cast,  dim3((CC * CC + 255) / 256), dim3(256), 0, stream, gw, gwb);
    hipLaunchKernelGGL(k1_rms_t, dim3(BB * (LL / 32)),        dim3(256), 0, stream,
                       x, pre_w, lw, xnt, adx);
    hipLaunchKernelGGL(k2_fused, dim3(LL / 128, 1, BB),       dim3(512), 0, stream,
                       gwb, xnt, gb, cw0, cb0, cw1, cb1, cw2, cb2, post_w, lw, adx, out);
}

// Round 6
// 78.643 us; speedup vs baseline: 2.2769x; 2.2769x over previous
//
#include <hip/hip_runtime.h>
#include <hip/hip_bf16.h>

#define BB 16
#define CC 512
#define LL 2048

typedef float f32x4 __attribute__((ext_vector_type(4)));
typedef short s16x8 __attribute__((ext_vector_type(8)));

static __device__ __forceinline__ float bf2f(unsigned short u) {
    union { unsigned int i; float f; } v; v.i = ((unsigned int)u) << 16; return v.f;
}
static __device__ __forceinline__ unsigned short f2bf(float f) {
    union { float fv; unsigned int i; } v; v.fv = f;
    unsigned int x = v.i;
    return (unsigned short)((x + 0x7FFFu + ((x >> 16) & 1u)) >> 16);  // RNE
}

// ---------------- K0: cast gate_w f32 -> bf16 [512][512] ----------------
__global__ void k0_cast(const float* __restrict__ gw, unsigned short* __restrict__ gwb) {
    int i = blockIdx.x * 256 + threadIdx.x;
    if (i < CC * CC) gwb[i] = f2bf(gw[i]);
}

// ------- K1: RMS over C per (b,l); write inv_rms + x_norm^T bf16 [B][L][C] -------
#define K1_ST 520   // ushort stride (1040 B, 16B-aligned)
__global__ __launch_bounds__(256) void k1_rms_t(
    const float* __restrict__ x, const float* __restrict__ pre_w,
    unsigned short* __restrict__ xnt, float* __restrict__ invr) {
    __shared__ unsigned short tile[32 * K1_ST];   // [l][c] bf16, 33.3 KB
    __shared__ float red[32 * 33];
    __shared__ float pwS[CC];
    __shared__ float ivS[32];
    const int tid = threadIdx.x;
    const int b  = blockIdx.x >> 6;      // 64 l-tiles of 32
    const int lt = blockIdx.x & 63;
    const int l0 = lt * 32;
    const float* xb = x + (size_t)(b * CC) * LL + l0;

    for (int i = tid; i < CC; i += 256) pwS[i] = pre_w[i];

    const int lq = tid & 7;      // l-quad: l = lq*4..+3
    const int cr = tid >> 3;     // 0..31
    f32x4 ssq = {0.f, 0.f, 0.f, 0.f};
    #pragma unroll
    for (int p = 0; p < 16; ++p) {
        int c = p * 32 + cr;
        f32x4 v = *(const f32x4*)(xb + (size_t)c * LL + lq * 4);
        #pragma unroll
        for (int r = 0; r < 4; ++r) {
            ssq[r] += v[r] * v[r];
            tile[(lq * 4 + r) * K1_ST + c] = f2bf(v[r]);
        }
    }
    #pragma unroll
    for (int r = 0; r < 4; ++r) red[(lq * 4 + r) * 33 + cr] = ssq[r];
    __syncthreads();
    if (tid < 32) {
        float s = 0.f;
        #pragma unroll
        for (int g = 0; g < 32; ++g) s += red[tid * 33 + g];
        float iv = rsqrtf(s * (1.0f / CC) + 1e-5f);
        ivS[tid] = iv;
        invr[b * LL + l0 + tid] = iv;
    }
    __syncthreads();
    unsigned short* xo = xnt + ((size_t)b * LL + l0) * CC;
    #pragma unroll
    for (int p = 0; p < 8; ++p) {
        int g = p * 256 + tid;          // 2048 granules of 8 ushorts
        int l = g >> 6, c8 = (g & 63) * 8;
        s16x8 t = *(const s16x8*)&tile[l * K1_ST + c8];
        f32x4 w0 = *(const f32x4*)&pwS[c8];
        f32x4 w1 = *(const f32x4*)&pwS[c8 + 4];
        float iv = ivS[l];
        s16x8 o;
        #pragma unroll
        for (int r = 0; r < 4; ++r) {
            o[r]     = (short)f2bf(bf2f((unsigned short)t[r])     * iv * w0[r]);
            o[r + 4] = (short)f2bf(bf2f((unsigned short)t[r + 4]) * iv * w1[r]);
        }
        *(s16x8*)(xo + (size_t)l * CC + c8) = o;
    }
}

// ------- K2: per-batch GEMM gate[d][l] = silu(sum_c gw[d][c]*xnT[l][c] + gb[d]) -------
// 256x256 tile, BK=32, 8 waves (2Mx4N, 128x64 each), 16 K-tiles.
// 3-buffer LDS (96KB), 2-tiles-ahead prefetch, counted vmcnt(8) (T4 — never
// drain to 0 in steady state). Granule XOR swizzle gin^((row>>1)&3) on both
// the pre-swizzled global source and the frag reads (rule #21).
__global__ __launch_bounds__(512, 2) void k2_gemm(
    const unsigned short* __restrict__ gwb,   // A [512][512] (d,c) row-major
    const unsigned short* __restrict__ xnt,   // B^T [B][2048][512] (l,c)
    const float* __restrict__ gate_b,
    unsigned short* __restrict__ gate) {      // out bf16 [B][512][2048]
    __shared__ unsigned short As[3][256 * 32];   // 3 x 16 KB
    __shared__ unsigned short Bs[3][256 * 32];   // 3 x 16 KB
    const int tid = threadIdx.x;
    const int w = tid >> 6, lane = tid & 63;
    const int lo = lane & 15, hi = lane >> 4;
    const int wm = w >> 2, wn = w & 3;           // 2M x 4N waves
    const int nt = blockIdx.x, mt = blockIdx.y, b = blockIdx.z;
    const int m0 = mt * 256, n0 = nt * 256;
    const unsigned short* Ab = gwb;
    const unsigned short* Bb = xnt + (size_t)b * LL * CC;

    // 1024 granules of 16B per operand tile; thread stages 2 of each (A,B).
    // LDS dest linear (byte = g*16, lane-contiguous); source k pre-swizzled.
    #define STG(kt_, buf_)                                                            \
        {                                                                             \
            _Pragma("unroll")                                                         \
            for (int s_ = 0; s_ < 2; ++s_) {                                          \
                int g_ = tid + s_ * 512;                                              \
                int row_ = g_ >> 2, gin_ = g_ & 3;                                    \
                int ks_ = (kt_) * 32 + ((gin_ ^ ((row_ >> 1) & 3)) * 8);              \
                __builtin_amdgcn_global_load_lds(                                     \
                    (const __attribute__((address_space(1))) void*)(Ab + (size_t)(m0 + row_) * CC + ks_), \
                    (__attribute__((address_space(3))) void*)(&As[buf_][g_ * 8]),     \
                    16, 0, 0);                                                        \
                __builtin_amdgcn_global_load_lds(                                     \
                    (const __attribute__((address_space(1))) void*)(Bb + (size_t)(n0 + row_) * CC + ks_), \
                    (__attribute__((address_space(3))) void*)(&Bs[buf_][g_ * 8]),     \
                    16, 0, 0);                                                        \
            }                                                                         \
        }

    f32x4 acc[8][4] = {};
    const int fsw = (lo >> 1) & 3;     // frag-read granule swizzle (matches source)

    STG(0, 0);
    STG(1, 1);
    #pragma unroll
    for (int kt = 0; kt < 16; ++kt) {
        const int buf = kt % 3;
        if (kt < 14) {
            STG(kt + 2, (kt + 2) % 3);
            asm volatile("s_waitcnt vmcnt(8)" ::: "memory");   // tile kt landed
        } else if (kt == 14) {
            asm volatile("s_waitcnt vmcnt(4)" ::: "memory");
        } else {
            asm volatile("s_waitcnt vmcnt(0)" ::: "memory");
        }
        __builtin_amdgcn_s_barrier();
        s16x8 af[8], bfr[4];
        #pragma unroll
        for (int mi = 0; mi < 8; ++mi)
            af[mi] = *(const s16x8*)&As[buf][(wm * 128 + mi * 16 + lo) * 32 + ((hi ^ fsw) * 8)];
        #pragma unroll
        for (int ni = 0; ni < 4; ++ni)
            bfr[ni] = *(const s16x8*)&Bs[buf][(wn * 64 + ni * 16 + lo) * 32 + ((hi ^ fsw) * 8)];
        __builtin_amdgcn_s_setprio(1);
        #pragma unroll
        for (int mi = 0; mi < 8; ++mi)
            #pragma unroll
            for (int ni = 0; ni < 4; ++ni)
                acc[mi][ni] = __builtin_amdgcn_mfma_f32_16x16x32_bf16(
                    af[mi], bfr[ni], acc[mi][ni], 0, 0, 0);
        __builtin_amdgcn_s_setprio(0);
        asm volatile("" ::: "memory");
        __builtin_amdgcn_s_barrier();   // all reads of buf done before overwrite
    }
    #undef STG

    // epilogue: +bias, SiLU, store bf16. D map: col=lane&15, row=(lane>>4)*4+r
    #pragma unroll
    for (int mi = 0; mi < 8; ++mi) {
        #pragma unroll
        for (int ni = 0; ni < 4; ++ni) {
            int n = n0 + wn * 64 + ni * 16 + lo;
            int d0 = m0 + wm * 128 + mi * 16 + hi * 4;
            #pragma unroll
            for (int r = 0; r < 4; ++r) {
                int d = d0 + r;
                float z = acc[mi][ni][r] + gate_b[d];
                float s = z / (1.0f + __expf(-z));
                gate[((size_t)(b * CC + d)) * LL + n] = f2bf(s);
            }
        }
    }
}

// ------- K3a: fused conv(7 taps)*gate partials over a 64-channel chunk -------
__global__ __launch_bounds__(256) void k3a(
    const float* __restrict__ x, const float* __restrict__ invr,
    const unsigned short* __restrict__ gate,
    const float* __restrict__ cw0, const float* __restrict__ cb0,
    const float* __restrict__ cw1, const float* __restrict__ cb1,
    const float* __restrict__ cw2, const float* __restrict__ cb2,
    const float* __restrict__ pre_w, const float* __restrict__ post_w,
    const float* __restrict__ lw, float* __restrict__ part) {
    __shared__ float tapS[64][8];
    __shared__ float biasS[64], preS[64], lwS[64], pwlwS[64];
    __shared__ float ivs[136];
    __shared__ float red[8][128][3];
    const int tid = threadIdx.x;
    const int lt = blockIdx.x;
    const int cc = blockIdx.y;
    const int b  = blockIdx.z;
    const int l0 = lt * 128;
    const int c0 = cc * 64;

    if (tid < 64) {
        int c = c0 + tid;
        float w10 = cw0[c*3], w11 = cw0[c*3+1], w12 = cw0[c*3+2];
        float w20 = cw1[c*3], w21 = cw1[c*3+1], w22 = cw1[c*3+2];
        float w40 = cw2[c*3], w41 = cw2[c*3+1], w42 = cw2[c*3+2];
        tapS[tid][0] = w40; tapS[tid][1] = w20; tapS[tid][2] = w10;
        tapS[tid][3] = w11 + w21 + w41;
        tapS[tid][4] = w12; tapS[tid][5] = w22; tapS[tid][6] = w42;
        biasS[tid] = cb0[c] + cb1[c] + cb2[c];
        preS[tid]  = pre_w[c];
        float lwc = lw[c];
        lwS[tid] = lwc;
        pwlwS[tid] = post_w[c] * lwc;
    }
    if (tid < 136) {
        int lg = l0 - 4 + tid;
        ivs[tid] = (lg >= 0 && lg < LL) ? invr[b * LL + lg] : 0.f;
    }
    __syncthreads();

    const int li = tid & 31, ci = tid >> 5;
    const int lq = l0 + li * 4;
    float iv[12];
    #pragma unroll
    for (int j = 0; j < 12; ++j) iv[j] = ivs[li * 4 + j];

    const int ia = (lq - 4 < 0) ? 0 : lq - 4;
    const int ic = (lq + 4 > LL - 4) ? LL - 4 : lq + 4;

    float ass[4] = {}, adp[4] = {}, adx[4] = {};
    const float* xbase = x + ((size_t)(b * CC + c0)) * LL;
    const unsigned short* gbase = gate + ((size_t)(b * CC + c0)) * LL;

    #pragma unroll
    for (int j = 0; j < 8; ++j) {
        const int cl = ci * 8 + j;
        const float* xr = xbase + (size_t)cl * LL;
        f32x4 xa = *(const f32x4*)(xr + ia);
        f32x4 xm = *(const f32x4*)(xr + lq);
        f32x4 xc = *(const f32x4*)(xr + ic);
        uint2 gu = *(const uint2*)(gbase + (size_t)cl * LL + lq);
        float g[4];
        g[0] = bf2f((unsigned short)(gu.x & 0xffff));
        g[1] = bf2f((unsigned short)(gu.x >> 16));
        g[2] = bf2f((unsigned short)(gu.y & 0xffff));
        g[3] = bf2f((unsigned short)(gu.y >> 16));
        float z[12];
        #pragma unroll
        for (int r = 0; r < 4; ++r) {
            z[r]     = xa[r] * iv[r];
            z[r + 4] = xm[r] * iv[r + 4];
            z[r + 8] = xc[r] * iv[r + 8];
        }
        const float t0 = tapS[cl][0], t1 = tapS[cl][1], t2 = tapS[cl][2],
                    t3 = tapS[cl][3], t4 = tapS[cl][4], t5 = tapS[cl][5],
                    t6 = tapS[cl][6];
        const float pre = preS[cl], bias = biasS[cl], pwlw = pwlwS[cl], lwc = lwS[cl];
        #pragma unroll
        for (int k = 0; k < 4; ++k) {
            float s = t0 * z[k] + t1 * z[k + 2] + t2 * z[k + 3] + t3 * z[k + 4]
                    + t4 * z[k + 5] + t5 * z[k + 6] + t6 * z[k + 8];
            float p = (pre * s + bias) * g[k];
            ass[k] += p * p;
            adp[k] += p * pwlw;
            adx[k] += xm[k] * lwc;
        }
    }
    #pragma unroll
    for (int k = 0; k < 4; ++k) {
        red[ci][li * 4 + k][0] = ass[k];
        red[ci][li * 4 + k][1] = adp[k];
        red[ci][li * 4 + k][2] = adx[k];
    }
    __syncthreads();
    if (tid < 128) {
        float s0 = 0.f, s1 = 0.f, s2 = 0.f;
        #pragma unroll
        for (int g2 = 0; g2 < 8; ++g2) {
            s0 += red[g2][tid][0];
            s1 += red[g2][tid][1];
            s2 += red[g2][tid][2];
        }
        float* pp = part + (((size_t)(b * 8 + cc)) * LL + l0 + tid) * 3;
        pp[0] = s0; pp[1] = s1; pp[2] = s2;
    }
}

// ------- K3b: combine 8 chunk-partials -> out -------
__global__ __launch_bounds__(256) void k3b(
    const float* __restrict__ part, float* __restrict__ out) {
    int gl = blockIdx.x * 256 + threadIdx.x;   // B*L = 32768
    int b = gl >> 11, l = gl & 2047;
    float s0 = 0.f, s1 = 0.f, s2 = 0.f;
    #pragma unroll
    for (int cc2 = 0; cc2 < 8; ++cc2) {
        const float* pp = part + (((size_t)(b * 8 + cc2)) * LL + l) * 3;
        s0 += pp[0]; s1 += pp[1]; s2 += pp[2];
    }
    out[gl] = s2 + rsqrtf(s0 * (1.0f / CC) + 1e-5f) * s1;
}

extern "C" void kernel_launch(void* const* d_in, const int* in_sizes, int n_in,
                              void* d_out, int out_size, void* d_ws, size_t ws_size,
                              hipStream_t stream) {
    const float* x      = (const float*)d_in[1];
    const float* pre_w  = (const float*)d_in[2];
    const float* cw0    = (const float*)d_in[3];
    const float* cb0    = (const float*)d_in[4];
    const float* cw1    = (const float*)d_in[5];
    const float* cb1    = (const float*)d_in[6];
    const float* cw2    = (const float*)d_in[7];
    const float* cb2    = (const float*)d_in[8];
    const float* gw     = (const float*)d_in[9];
    const float* gb     = (const float*)d_in[10];
    const float* post_w = (const float*)d_in[11];
    const float* lw     = (const float*)d_in[12];
    float* out = (float*)d_out;

    // ws layout (bytes): gw_bf16 0..524288 | x_norm_T 524288..34078720 |
    // inv_rms ..34209792 | gate ..67764224
    // part (3.1MB) aliases x_norm_T (dead after k2).
    char* ws = (char*)d_ws;
    unsigned short* gwb  = (unsigned short*)(ws);
    unsigned short* xnt  = (unsigned short*)(ws + 524288);
    float*          invr = (float*)(ws + 524288 + 33554432);
    unsigned short* gate = (unsigned short*)(ws + 524288 + 33554432 + 131072);
    float*          part = (float*)(ws + 524288);   // alias, dead xnt

    hipLaunchKernelGGL(k0_cast,  dim3((CC * CC + 255) / 256), dim3(256), 0, stream, gw, gwb);
    hipLaunchKernelGGL(k1_rms_t, dim3(BB * (LL / 32)),        dim3(256), 0, stream, x, pre_w, xnt, invr);
    hipLaunchKernelGGL(k2_gemm,  dim3(LL / 256, CC / 256, BB), dim3(512), 0, stream, gwb, xnt, gb, gate);
    hipLaunchKernelGGL(k3a,      dim3(LL / 128, CC / 64, BB), dim3(256), 0, stream,
                       x, invr, gate, cw0, cb0, cw1, cb1, cw2, cb2, pre_w, post_w, lw, part);
    hipLaunchKernelGGL(k3b,      dim3(BB * LL / 256),         dim3(256), 0, stream, part, out);
}